// Round 3
// baseline (220.425 us; speedup 1.0000x reference)
//
#include <hip/hip_runtime.h>
#include <math.h>

#define D_IN 131072
#define H 512
#define G4 2048      // 4*H
#define OUTN 16384   // 128*128

// ---- output flat offsets ----
// g: [0,16384)  step:16384  m_c:16385  h0:@16386  h1:@16898  c0:@17410  c1:@17922
#define OFF_STEP 16384
#define OFF_MC   16385
#define OFF_H0   16386
#define OFF_H1   16898
#define OFF_C0   17410
#define OFF_C1   17922

__device__ __forceinline__ float sigmoidf_(float x) {
    return 1.0f / (1.0f + __expf(-x));
}

__device__ __forceinline__ float dot4(float4 a, float4 b) {
    return a.x*b.x + a.y*b.y + a.z*b.z + a.w*b.w;
}

// ---------------------------------------------------------------------------
// K1: gates1[r] = W_ih1[r,:].grad + W_hh1[r,:].hidden0 + b_ih1 + b_hh1
// 512 blocks x 1024 threads. Each block: 4 rows x 4 K-quarter waves.
// x (= U||V) staged in 32 KB LDS chunks -> x global traffic 1 GB -> 256 MB,
// and W-loads no longer interleave with global x loads.
// ---------------------------------------------------------------------------
#define K1_ROWS 4
__global__ __launch_bounds__(1024) void k_gemv1(
    const float* __restrict__ U, const float* __restrict__ V,
    const float* __restrict__ Wih, const float* __restrict__ Whh,
    const float* __restrict__ bih, const float* __restrict__ bhh,
    const float* __restrict__ hidden, float* __restrict__ gates)
{
    __shared__ float4 xs[2048];   // 8192 floats = 32 KB
    __shared__ float red[16];
    const int tid  = threadIdx.x;
    const int wv   = tid >> 6;        // 0..15
    const int lane = tid & 63;
    const int rloc = wv >> 2;         // 0..3  (row within block)
    const int q    = wv & 3;          // 0..3  (K quarter)
    const int row  = blockIdx.x * K1_ROWS + rloc;
    const float4* __restrict__ Wrow = (const float4*)(Wih + (size_t)row * D_IN);
    const float4* __restrict__ U4 = (const float4*)U;
    const float4* __restrict__ V4 = (const float4*)V;
    float acc = 0.0f;
    // 16 chunks of 2048 float4 (8192 floats). Chunks 0..7 = U, 8..15 = V.
    for (int c = 0; c < 16; ++c) {
        const float4* __restrict__ src = (c < 8) ? (U4 + (c << 11))
                                                 : (V4 + ((c - 8) << 11));
        __syncthreads();               // previous chunk fully consumed
        xs[tid]        = src[tid];
        xs[tid + 1024] = src[tid + 1024];
        __syncthreads();
        const float4* __restrict__ Wc = Wrow + (c << 11);
        const int base = (q << 9) + lane;   // quarter offset
        #pragma unroll
        for (int k = 0; k < 8; ++k) {
            const int j = base + (k << 6);
            acc += dot4(Wc[j], xs[j]);
        }
    }
    // recurrent part: one wave (q==0) per row
    if (q == 0) {
        const float4* __restrict__ Wh4 = (const float4*)(Whh + (size_t)row * H);
        const float4* h4 = (const float4*)hidden;   // hidden[0]
        acc += dot4(Wh4[lane], h4[lane]) + dot4(Wh4[lane + 64], h4[lane + 64]);
    }
    #pragma unroll
    for (int off = 32; off > 0; off >>= 1) acc += __shfl_down(acc, off);
    if (lane == 0) red[wv] = acc;
    __syncthreads();
    if (tid < K1_ROWS) {
        const int b = tid << 2;       // partials for row tid at red[4t..4t+3]
        const int r = blockIdx.x * K1_ROWS + tid;
        gates[r] = red[b] + red[b+1] + red[b+2] + red[b+3] + bih[r] + bhh[r];
    }
}

// ---------------------------------------------------------------------------
// K2: fused cell1 + gemv2. 128 blocks x 1024 threads (16 waves = 16 rows).
// Every block recomputes h0 from gates1 into LDS; block 0 writes h0/c0 + m_c.
// ---------------------------------------------------------------------------
__global__ __launch_bounds__(1024) void k_l2fused(
    const float* __restrict__ gates1, const float* __restrict__ cell_in,
    const float* __restrict__ hidden,
    const float* __restrict__ Wih2, const float* __restrict__ Whh2,
    const float* __restrict__ bih2, const float* __restrict__ bhh2,
    const float* __restrict__ W3, const float* __restrict__ b3,
    float* __restrict__ gates2, float* __restrict__ out)
{
    __shared__ float h0s[H];
    __shared__ float red[16];
    const int tid = threadIdx.x;
    if (tid < H) {
        float ig = sigmoidf_(gates1[tid]);
        float fg = sigmoidf_(gates1[H + tid]);
        float gg = tanhf(gates1[2*H + tid]);
        float og = sigmoidf_(gates1[3*H + tid]);
        float c  = fg * cell_in[tid] + ig * gg;   // cell[0]
        float h  = og * tanhf(c);
        h0s[tid] = h;
        if (blockIdx.x == 0) {
            out[OFF_H0 + tid] = h;
            out[OFF_C0 + tid] = c;
        }
    }
    __syncthreads();
    const int wv = tid >> 6, lane = tid & 63;
    const int row = blockIdx.x * 16 + wv;
    const float4* __restrict__ Wr = (const float4*)(Wih2 + (size_t)row * H);
    const float4* __restrict__ Hr = (const float4*)(Whh2 + (size_t)row * H);
    const float4* h4 = (const float4*)h0s;
    const float4* __restrict__ y4 = (const float4*)(hidden + H);  // hidden[1]
    float acc = dot4(Wr[lane],      h4[lane])      + dot4(Hr[lane],      y4[lane])
              + dot4(Wr[lane + 64], h4[lane + 64]) + dot4(Hr[lane + 64], y4[lane + 64]);
    #pragma unroll
    for (int off = 32; off > 0; off >>= 1) acc += __shfl_down(acc, off);
    if (lane == 0) gates2[row] = acc + bih2[row] + bhh2[row];

    if (blockIdx.x == 0) {
        // m_c = clip(2*clip(h0.W3 + b3, 0, 1), 0, 1)
        float p = (tid < H) ? h0s[tid] * W3[tid] : 0.0f;
        #pragma unroll
        for (int off = 32; off > 0; off >>= 1) p += __shfl_down(p, off);
        if (lane == 0) red[wv] = p;
        __syncthreads();
        if (tid == 0) {
            float v = b3[0];
            #pragma unroll
            for (int i = 0; i < 16; ++i) v += red[i];
            v = fminf(fmaxf(v, 0.0f), 1.0f);
            out[OFF_MC] = fminf(2.0f * v, 1.0f);
        }
    }
}

// ---------------------------------------------------------------------------
// K2b: cell2 -> h1 (ws + out), c1 (out), step_size. 1 block x 512 threads.
// ---------------------------------------------------------------------------
__global__ __launch_bounds__(512) void k_cell2(
    const float* __restrict__ gates2, const float* __restrict__ cell_in,
    const float* __restrict__ W2, const float* __restrict__ b2,
    float* __restrict__ h1, float* __restrict__ out)
{
    __shared__ float s[8];
    const int j = threadIdx.x;
    float ig = sigmoidf_(gates2[j]);
    float fg = sigmoidf_(gates2[H + j]);
    float gg = tanhf(gates2[2*H + j]);
    float og = sigmoidf_(gates2[3*H + j]);
    float c  = fg * cell_in[H + j] + ig * gg;  // cell[1]
    float h  = og * tanhf(c);
    h1[j] = h;
    out[OFF_H1 + j] = h;
    out[OFF_C1 + j] = c;
    float p = h * W2[j];
    #pragma unroll
    for (int off = 32; off > 0; off >>= 1) p += __shfl_down(p, off);
    if ((j & 63) == 0) s[j >> 6] = p;
    __syncthreads();
    if (j == 0) {
        float v = s[0]+s[1]+s[2]+s[3]+s[4]+s[5]+s[6]+s[7] + b2[0];
        out[OFF_STEP] = fminf(fmaxf(v, 1e-7f), 0.005f);
    }
}

// ---------------------------------------------------------------------------
// K3: g[r] = W1[r,:].h1 + b1[r]. Pure GEMV, one wave per row, no LDS/sync.
// 4096 blocks x 256 threads. h1 read from global (L2-hot, 2 KB).
// ---------------------------------------------------------------------------
__global__ __launch_bounds__(256) void k_out_g(
    const float* __restrict__ W1, const float* __restrict__ b1,
    const float* __restrict__ h1, float* __restrict__ out)
{
    const int wave = (blockIdx.x * 256 + threadIdx.x) >> 6;
    const int lane = threadIdx.x & 63;
    const float4* __restrict__ Wr = (const float4*)(W1 + (size_t)wave * H);
    const float4* x4 = (const float4*)h1;
    float acc = dot4(Wr[lane], x4[lane]) + dot4(Wr[lane + 64], x4[lane + 64]);
    #pragma unroll
    for (int off = 32; off > 0; off >>= 1) acc += __shfl_down(acc, off);
    if (lane == 0) out[wave] = acc + b1[wave];
}

extern "C" void kernel_launch(void* const* d_in, const int* in_sizes, int n_in,
                              void* d_out, int out_size, void* d_ws, size_t ws_size,
                              hipStream_t stream) {
    const float* dL_dU  = (const float*)d_in[0];
    const float* dL_dV  = (const float*)d_in[1];
    const float* hidden = (const float*)d_in[2];
    const float* cell   = (const float*)d_in[3];
    const float* W_ih1  = (const float*)d_in[4];
    const float* W_hh1  = (const float*)d_in[5];
    const float* b_ih1  = (const float*)d_in[6];
    const float* b_hh1  = (const float*)d_in[7];
    const float* W_ih2  = (const float*)d_in[8];
    const float* W_hh2  = (const float*)d_in[9];
    const float* b_ih2  = (const float*)d_in[10];
    const float* b_hh2  = (const float*)d_in[11];
    const float* W1     = (const float*)d_in[12];
    const float* b1     = (const float*)d_in[13];
    const float* W2     = (const float*)d_in[14];
    const float* b2     = (const float*)d_in[15];
    const float* W3     = (const float*)d_in[16];
    const float* b3     = (const float*)d_in[17];

    float* out = (float*)d_out;
    float* ws  = (float*)d_ws;
    float* gates1 = ws;             // 2048
    float* gates2 = ws + 2048;      // 2048
    float* h1     = ws + 4096;      // 512

    k_gemv1<<<G4 / K1_ROWS, 1024, 0, stream>>>(dL_dU, dL_dV, W_ih1, W_hh1,
                                               b_ih1, b_hh1, hidden, gates1);
    k_l2fused<<<G4 / 16, 1024, 0, stream>>>(gates1, cell, hidden,
                                            W_ih2, W_hh2, b_ih2, b_hh2,
                                            W3, b3, gates2, out);
    k_cell2<<<1, 512, 0, stream>>>(gates2, cell, W2, b2, h1, out);
    k_out_g<<<OUTN / 4, 256, 0, stream>>>(W1, b1, h1, out);
    (void)in_sizes; (void)n_in; (void)out_size; (void)ws_size;
}

// Round 4
// 219.210 us; speedup vs baseline: 1.0055x; 1.0055x over previous
//
#include <hip/hip_runtime.h>
#include <math.h>

#define D_IN 131072
#define H 512
#define G4 2048      // 4*H
#define OUTN 16384   // 128*128
#define NF4 32768    // D_IN/4 float4 per W row
#define KSLC 2048    // float4 per K-slice (NF4/16)

// ---- output flat offsets ----
#define OFF_STEP 16384
#define OFF_MC   16385
#define OFF_H0   16386
#define OFF_H1   16898
#define OFF_C0   17410
#define OFF_C1   17922

__device__ __forceinline__ float sigmoidf_(float x) {
    return 1.0f / (1.0f + __expf(-x));
}

__device__ __forceinline__ float dot4(float4 a, float4 b) {
    return a.x*b.x + a.y*b.y + a.z*b.z + a.w*b.w;
}

// ---------------------------------------------------------------------------
// K1a: register-blocked partial GEMV. 2048 blocks x 256 threads = 8192 waves.
// Wave w: row-group rg = w>>4 (rows 4rg..4rg+3), K-slice ks = w&15
// (float4 [ks*2048, ks*2048+2048)). Each x float4 loaded ONCE per wave and
// reused for 4 rows in registers. No barriers, no LDS, no atomics.
// partial[r*16 + ks] = sum over slice.
// ---------------------------------------------------------------------------
__global__ __launch_bounds__(256) void k_gemv1_part(
    const float* __restrict__ U, const float* __restrict__ V,
    const float* __restrict__ Wih, float* __restrict__ partial)
{
    const int wg   = blockIdx.x * 4 + (threadIdx.x >> 6);
    const int lane = threadIdx.x & 63;
    const int rg   = wg >> 4;       // 0..511
    const int ks   = wg & 15;       // 0..15
    const float4* __restrict__ xs =
        (ks < 8) ? ((const float4*)U + (ks << 11))
                 : ((const float4*)V + ((ks - 8) << 11));
    const float4* __restrict__ W0 =
        (const float4*)Wih + (size_t)(rg * 4) * NF4 + (ks << 11);
    const float4* __restrict__ W1r = W0 + NF4;
    const float4* __restrict__ W2r = W1r + NF4;
    const float4* __restrict__ W3r = W2r + NF4;
    float a0 = 0.f, a1 = 0.f, a2 = 0.f, a3 = 0.f;
    #pragma unroll 2
    for (int i = lane; i < KSLC; i += 64) {
        float4 xv = xs[i];
        a0 += dot4(W0[i], xv);
        a1 += dot4(W1r[i], xv);
        a2 += dot4(W2r[i], xv);
        a3 += dot4(W3r[i], xv);
    }
    #pragma unroll
    for (int off = 32; off > 0; off >>= 1) {
        a0 += __shfl_down(a0, off);
        a1 += __shfl_down(a1, off);
        a2 += __shfl_down(a2, off);
        a3 += __shfl_down(a3, off);
    }
    if (lane == 0) {
        float* p = partial + (size_t)(rg * 4) * 16 + ks;
        p[0]  = a0;
        p[16] = a1;
        p[32] = a2;
        p[48] = a3;
    }
}

// ---------------------------------------------------------------------------
// K1b: combine. One wave per row (512 blocks x 256). gates1[r] =
// sum16 partial[r][*] + Whh1[r,:].hidden0 + b_ih1[r] + b_hh1[r].
// ---------------------------------------------------------------------------
__global__ __launch_bounds__(256) void k_gemv1_comb(
    const float* __restrict__ partial, const float* __restrict__ Whh,
    const float* __restrict__ hidden, const float* __restrict__ bih,
    const float* __restrict__ bhh, float* __restrict__ gates)
{
    const int r    = (blockIdx.x * 256 + threadIdx.x) >> 6;
    const int lane = threadIdx.x & 63;
    const float4* __restrict__ Wh = (const float4*)(Whh + (size_t)r * H);
    const float4* h4 = (const float4*)hidden;   // hidden[0]
    float acc = dot4(Wh[lane], h4[lane]) + dot4(Wh[lane + 64], h4[lane + 64]);
    if (lane < 16) acc += partial[r * 16 + lane];
    #pragma unroll
    for (int off = 32; off > 0; off >>= 1) acc += __shfl_down(acc, off);
    if (lane == 0) gates[r] = acc + bih[r] + bhh[r];
}

// ---------------------------------------------------------------------------
// K2: fused cell1 + gemv2. 128 blocks x 1024 threads (16 waves = 16 rows).
// ---------------------------------------------------------------------------
__global__ __launch_bounds__(1024) void k_l2fused(
    const float* __restrict__ gates1, const float* __restrict__ cell_in,
    const float* __restrict__ hidden,
    const float* __restrict__ Wih2, const float* __restrict__ Whh2,
    const float* __restrict__ bih2, const float* __restrict__ bhh2,
    const float* __restrict__ W3, const float* __restrict__ b3,
    float* __restrict__ gates2, float* __restrict__ out)
{
    __shared__ float h0s[H];
    __shared__ float red[16];
    const int tid = threadIdx.x;
    if (tid < H) {
        float ig = sigmoidf_(gates1[tid]);
        float fg = sigmoidf_(gates1[H + tid]);
        float gg = tanhf(gates1[2*H + tid]);
        float og = sigmoidf_(gates1[3*H + tid]);
        float c  = fg * cell_in[tid] + ig * gg;   // cell[0]
        float h  = og * tanhf(c);
        h0s[tid] = h;
        if (blockIdx.x == 0) {
            out[OFF_H0 + tid] = h;
            out[OFF_C0 + tid] = c;
        }
    }
    __syncthreads();
    const int wv = tid >> 6, lane = tid & 63;
    const int row = blockIdx.x * 16 + wv;
    const float4* __restrict__ Wr = (const float4*)(Wih2 + (size_t)row * H);
    const float4* __restrict__ Hr = (const float4*)(Whh2 + (size_t)row * H);
    const float4* h4 = (const float4*)h0s;
    const float4* __restrict__ y4 = (const float4*)(hidden + H);  // hidden[1]
    float acc = dot4(Wr[lane],      h4[lane])      + dot4(Hr[lane],      y4[lane])
              + dot4(Wr[lane + 64], h4[lane + 64]) + dot4(Hr[lane + 64], y4[lane + 64]);
    #pragma unroll
    for (int off = 32; off > 0; off >>= 1) acc += __shfl_down(acc, off);
    if (lane == 0) gates2[row] = acc + bih2[row] + bhh2[row];

    if (blockIdx.x == 0) {
        float p = (tid < H) ? h0s[tid] * W3[tid] : 0.0f;
        #pragma unroll
        for (int off = 32; off > 0; off >>= 1) p += __shfl_down(p, off);
        if (lane == 0) red[wv] = p;
        __syncthreads();
        if (tid == 0) {
            float v = b3[0];
            #pragma unroll
            for (int i = 0; i < 16; ++i) v += red[i];
            v = fminf(fmaxf(v, 0.0f), 1.0f);
            out[OFF_MC] = fminf(2.0f * v, 1.0f);
        }
    }
}

// ---------------------------------------------------------------------------
// K2b: cell2 -> h1 (ws + out), c1 (out), step_size. 1 block x 512 threads.
// ---------------------------------------------------------------------------
__global__ __launch_bounds__(512) void k_cell2(
    const float* __restrict__ gates2, const float* __restrict__ cell_in,
    const float* __restrict__ W2, const float* __restrict__ b2,
    float* __restrict__ h1, float* __restrict__ out)
{
    __shared__ float s[8];
    const int j = threadIdx.x;
    float ig = sigmoidf_(gates2[j]);
    float fg = sigmoidf_(gates2[H + j]);
    float gg = tanhf(gates2[2*H + j]);
    float og = sigmoidf_(gates2[3*H + j]);
    float c  = fg * cell_in[H + j] + ig * gg;  // cell[1]
    float h  = og * tanhf(c);
    h1[j] = h;
    out[OFF_H1 + j] = h;
    out[OFF_C1 + j] = c;
    float p = h * W2[j];
    #pragma unroll
    for (int off = 32; off > 0; off >>= 1) p += __shfl_down(p, off);
    if ((j & 63) == 0) s[j >> 6] = p;
    __syncthreads();
    if (j == 0) {
        float v = s[0]+s[1]+s[2]+s[3]+s[4]+s[5]+s[6]+s[7] + b2[0];
        out[OFF_STEP] = fminf(fmaxf(v, 1e-7f), 0.005f);
    }
}

// ---------------------------------------------------------------------------
// K3: g[r] = W1[r,:].h1 + b1[r]. One wave per row, no LDS/sync.
// ---------------------------------------------------------------------------
__global__ __launch_bounds__(256) void k_out_g(
    const float* __restrict__ W1, const float* __restrict__ b1,
    const float* __restrict__ h1, float* __restrict__ out)
{
    const int wave = (blockIdx.x * 256 + threadIdx.x) >> 6;
    const int lane = threadIdx.x & 63;
    const float4* __restrict__ Wr = (const float4*)(W1 + (size_t)wave * H);
    const float4* x4 = (const float4*)h1;
    float acc = dot4(Wr[lane], x4[lane]) + dot4(Wr[lane + 64], x4[lane + 64]);
    #pragma unroll
    for (int off = 32; off > 0; off >>= 1) acc += __shfl_down(acc, off);
    if (lane == 0) out[wave] = acc + b1[wave];
}

extern "C" void kernel_launch(void* const* d_in, const int* in_sizes, int n_in,
                              void* d_out, int out_size, void* d_ws, size_t ws_size,
                              hipStream_t stream) {
    const float* dL_dU  = (const float*)d_in[0];
    const float* dL_dV  = (const float*)d_in[1];
    const float* hidden = (const float*)d_in[2];
    const float* cell   = (const float*)d_in[3];
    const float* W_ih1  = (const float*)d_in[4];
    const float* W_hh1  = (const float*)d_in[5];
    const float* b_ih1  = (const float*)d_in[6];
    const float* b_hh1  = (const float*)d_in[7];
    const float* W_ih2  = (const float*)d_in[8];
    const float* W_hh2  = (const float*)d_in[9];
    const float* b_ih2  = (const float*)d_in[10];
    const float* b_hh2  = (const float*)d_in[11];
    const float* W1     = (const float*)d_in[12];
    const float* b1     = (const float*)d_in[13];
    const float* W2     = (const float*)d_in[14];
    const float* b2     = (const float*)d_in[15];
    const float* W3     = (const float*)d_in[16];
    const float* b3     = (const float*)d_in[17];

    float* out = (float*)d_out;
    float* ws  = (float*)d_ws;
    float* partial = ws;              // 32768 (2048 rows x 16 slices)
    float* gates1  = ws + 32768;      // 2048
    float* gates2  = ws + 32768 + 2048;
    float* h1      = ws + 32768 + 4096;

    k_gemv1_part<<<2048, 256, 0, stream>>>(dL_dU, dL_dV, W_ih1, partial);
    k_gemv1_comb<<<512, 256, 0, stream>>>(partial, W_hh1, hidden,
                                          b_ih1, b_hh1, gates1);
    k_l2fused<<<G4 / 16, 1024, 0, stream>>>(gates1, cell, hidden,
                                            W_ih2, W_hh2, b_ih2, b_hh2,
                                            W3, b3, gates2, out);
    k_cell2<<<1, 512, 0, stream>>>(gates2, cell, W2, b2, h1, out);
    k_out_g<<<OUTN / 4, 256, 0, stream>>>(W1, b1, h1, out);
    (void)in_sizes; (void)n_in; (void)out_size; (void)ws_size;
}

// Round 5
// 195.093 us; speedup vs baseline: 1.1298x; 1.1236x over previous
//
#include <hip/hip_runtime.h>
#include <math.h>

#define D_IN 131072
#define H 512
#define G4 2048      // 4*H
#define OUTN 16384   // 128*128

// ---- output flat offsets ----
// g: [0,16384)  step:16384  m_c:16385  h0:@16386  h1:@16898  c0:@17410  c1:@17922
#define OFF_STEP 16384
#define OFF_MC   16385
#define OFF_H0   16386
#define OFF_H1   16898
#define OFF_C0   17410
#define OFF_C1   17922

__device__ __forceinline__ float sigmoidf_(float x) {
    return 1.0f / (1.0f + __expf(-x));
}

__device__ __forceinline__ float dot4(float4 a, float4 b) {
    return a.x*b.x + a.y*b.y + a.z*b.z + a.w*b.w;
}

// non-temporal float4 load (single-use weight streams: don't pollute L2)
typedef float f4v __attribute__((ext_vector_type(4)));
__device__ __forceinline__ float4 ntload4(const float4* p) {
    f4v v = __builtin_nontemporal_load((const f4v*)p);
    float4 r; r.x = v.x; r.y = v.y; r.z = v.z; r.w = v.w;
    return r;
}

// ---------------------------------------------------------------------------
// K1: gates1[r] = W_ih1[r,:].grad + W_hh1[r,:].hidden0 + b_ih1[r] + b_hh1[r]
// One 256-thread block per row (2048 blocks) — R2 structure, W loads NT.
// ---------------------------------------------------------------------------
__global__ __launch_bounds__(256) void k_gemv1(
    const float* __restrict__ U, const float* __restrict__ V,
    const float* __restrict__ Wih, const float* __restrict__ Whh,
    const float* __restrict__ bih, const float* __restrict__ bhh,
    const float* __restrict__ hidden, float* __restrict__ gates)
{
    const int r = blockIdx.x;
    const int t = threadIdx.x;
    const float4* __restrict__ Wrow = (const float4*)(Wih + (size_t)r * D_IN);
    const float4* __restrict__ U4 = (const float4*)U;
    const float4* __restrict__ V4 = (const float4*)V;
    float acc = 0.0f;
    #pragma unroll 4
    for (int idx = t; idx < 16384; idx += 256) {
        acc += dot4(ntload4(&Wrow[idx]), U4[idx]);
    }
    #pragma unroll 4
    for (int idx = t; idx < 16384; idx += 256) {
        acc += dot4(ntload4(&Wrow[idx + 16384]), V4[idx]);
    }
    if (t < 128) {
        const float4* Wh4 = (const float4*)(Whh + (size_t)r * H);
        const float4* h4  = (const float4*)hidden;  // hidden[0]
        acc += dot4(ntload4(&Wh4[t]), h4[t]);
    }
    #pragma unroll
    for (int off = 32; off > 0; off >>= 1) acc += __shfl_down(acc, off);
    __shared__ float s[4];
    if ((t & 63) == 0) s[t >> 6] = acc;
    __syncthreads();
    if (t == 0) {
        gates[r] = s[0] + s[1] + s[2] + s[3] + bih[r] + bhh[r];
    }
}

// ---------------------------------------------------------------------------
// K2: fused cell1 + gemv2. 128 blocks x 1024 threads (16 waves = 16 rows).
// ---------------------------------------------------------------------------
__global__ __launch_bounds__(1024) void k_l2fused(
    const float* __restrict__ gates1, const float* __restrict__ cell_in,
    const float* __restrict__ hidden,
    const float* __restrict__ Wih2, const float* __restrict__ Whh2,
    const float* __restrict__ bih2, const float* __restrict__ bhh2,
    const float* __restrict__ W3, const float* __restrict__ b3,
    float* __restrict__ gates2, float* __restrict__ out)
{
    __shared__ float h0s[H];
    __shared__ float red[16];
    const int tid = threadIdx.x;
    if (tid < H) {
        float ig = sigmoidf_(gates1[tid]);
        float fg = sigmoidf_(gates1[H + tid]);
        float gg = tanhf(gates1[2*H + tid]);
        float og = sigmoidf_(gates1[3*H + tid]);
        float c  = fg * cell_in[tid] + ig * gg;   // cell[0]
        float h  = og * tanhf(c);
        h0s[tid] = h;
        if (blockIdx.x == 0) {
            out[OFF_H0 + tid] = h;
            out[OFF_C0 + tid] = c;
        }
    }
    __syncthreads();
    const int wv = tid >> 6, lane = tid & 63;
    const int row = blockIdx.x * 16 + wv;
    const float4* __restrict__ Wr = (const float4*)(Wih2 + (size_t)row * H);
    const float4* __restrict__ Hr = (const float4*)(Whh2 + (size_t)row * H);
    const float4* h4 = (const float4*)h0s;
    const float4* __restrict__ y4 = (const float4*)(hidden + H);  // hidden[1]
    float acc = dot4(ntload4(&Wr[lane]),      h4[lane])
              + dot4(ntload4(&Hr[lane]),      y4[lane])
              + dot4(ntload4(&Wr[lane + 64]), h4[lane + 64])
              + dot4(ntload4(&Hr[lane + 64]), y4[lane + 64]);
    #pragma unroll
    for (int off = 32; off > 0; off >>= 1) acc += __shfl_down(acc, off);
    if (lane == 0) gates2[row] = acc + bih2[row] + bhh2[row];

    if (blockIdx.x == 0) {
        float p = (tid < H) ? h0s[tid] * W3[tid] : 0.0f;
        #pragma unroll
        for (int off = 32; off > 0; off >>= 1) p += __shfl_down(p, off);
        if (lane == 0) red[wv] = p;
        __syncthreads();
        if (tid == 0) {
            float v = b3[0];
            #pragma unroll
            for (int i = 0; i < 16; ++i) v += red[i];
            v = fminf(fmaxf(v, 0.0f), 1.0f);
            out[OFF_MC] = fminf(2.0f * v, 1.0f);
        }
    }
}

// ---------------------------------------------------------------------------
// K2b: cell2 -> h1 (ws + out), c1 (out), step_size. 1 block x 512 threads.
// ---------------------------------------------------------------------------
__global__ __launch_bounds__(512) void k_cell2(
    const float* __restrict__ gates2, const float* __restrict__ cell_in,
    const float* __restrict__ W2, const float* __restrict__ b2,
    float* __restrict__ h1, float* __restrict__ out)
{
    __shared__ float s[8];
    const int j = threadIdx.x;
    float ig = sigmoidf_(gates2[j]);
    float fg = sigmoidf_(gates2[H + j]);
    float gg = tanhf(gates2[2*H + j]);
    float og = sigmoidf_(gates2[3*H + j]);
    float c  = fg * cell_in[H + j] + ig * gg;  // cell[1]
    float h  = og * tanhf(c);
    h1[j] = h;
    out[OFF_H1 + j] = h;
    out[OFF_C1 + j] = c;
    float p = h * W2[j];
    #pragma unroll
    for (int off = 32; off > 0; off >>= 1) p += __shfl_down(p, off);
    if ((j & 63) == 0) s[j >> 6] = p;
    __syncthreads();
    if (j == 0) {
        float v = s[0]+s[1]+s[2]+s[3]+s[4]+s[5]+s[6]+s[7] + b2[0];
        out[OFF_STEP] = fminf(fmaxf(v, 1e-7f), 0.005f);
    }
}

// ---------------------------------------------------------------------------
// K3: g[r] = W1[r,:].h1 + b1[r]. One wave per row, W1 loads NT.
// ---------------------------------------------------------------------------
__global__ __launch_bounds__(256) void k_out_g(
    const float* __restrict__ W1, const float* __restrict__ b1,
    const float* __restrict__ h1, float* __restrict__ out)
{
    const int wave = (blockIdx.x * 256 + threadIdx.x) >> 6;
    const int lane = threadIdx.x & 63;
    const float4* __restrict__ Wr = (const float4*)(W1 + (size_t)wave * H);
    const float4* x4 = (const float4*)h1;
    float acc = dot4(ntload4(&Wr[lane]),      x4[lane])
              + dot4(ntload4(&Wr[lane + 64]), x4[lane + 64]);
    #pragma unroll
    for (int off = 32; off > 0; off >>= 1) acc += __shfl_down(acc, off);
    if (lane == 0) out[wave] = acc + b1[wave];
}

extern "C" void kernel_launch(void* const* d_in, const int* in_sizes, int n_in,
                              void* d_out, int out_size, void* d_ws, size_t ws_size,
                              hipStream_t stream) {
    const float* dL_dU  = (const float*)d_in[0];
    const float* dL_dV  = (const float*)d_in[1];
    const float* hidden = (const float*)d_in[2];
    const float* cell   = (const float*)d_in[3];
    const float* W_ih1  = (const float*)d_in[4];
    const float* W_hh1  = (const float*)d_in[5];
    const float* b_ih1  = (const float*)d_in[6];
    const float* b_hh1  = (const float*)d_in[7];
    const float* W_ih2  = (const float*)d_in[8];
    const float* W_hh2  = (const float*)d_in[9];
    const float* b_ih2  = (const float*)d_in[10];
    const float* b_hh2  = (const float*)d_in[11];
    const float* W1     = (const float*)d_in[12];
    const float* b1     = (const float*)d_in[13];
    const float* W2     = (const float*)d_in[14];
    const float* b2     = (const float*)d_in[15];
    const float* W3     = (const float*)d_in[16];
    const float* b3     = (const float*)d_in[17];

    float* out = (float*)d_out;
    float* ws  = (float*)d_ws;
    float* gates1 = ws;             // 2048
    float* gates2 = ws + 2048;      // 2048
    float* h1     = ws + 4096;      // 512

    k_gemv1<<<G4, 256, 0, stream>>>(dL_dU, dL_dV, W_ih1, W_hh1, b_ih1, b_hh1,
                                    hidden, gates1);
    k_l2fused<<<G4 / 16, 1024, 0, stream>>>(gates1, cell, hidden,
                                            W_ih2, W_hh2, b_ih2, b_hh2,
                                            W3, b3, gates2, out);
    k_cell2<<<1, 512, 0, stream>>>(gates2, cell, W2, b2, h1, out);
    k_out_g<<<OUTN / 4, 256, 0, stream>>>(W1, b1, h1, out);
    (void)in_sizes; (void)n_in; (void)out_size; (void)ws_size;
}

// Round 6
// 187.971 us; speedup vs baseline: 1.1727x; 1.0379x over previous
//
#include <hip/hip_runtime.h>
#include <math.h>

#define D_IN 131072
#define H 512
#define G4 2048      // 4*H
#define OUTN 16384   // 128*128

// ---- output flat offsets ----
// g: [0,16384)  step:16384  m_c:16385  h0:@16386  h1:@16898  c0:@17410  c1:@17922
#define OFF_STEP 16384
#define OFF_MC   16385
#define OFF_H0   16386
#define OFF_H1   16898
#define OFF_C0   17410
#define OFF_C1   17922

__device__ __forceinline__ float sigmoidf_(float x) {
    return 1.0f / (1.0f + __expf(-x));
}

__device__ __forceinline__ float dot4(float4 a, float4 b) {
    return a.x*b.x + a.y*b.y + a.z*b.z + a.w*b.w;
}

// non-temporal float4 load (single-use weight streams: don't pollute L2)
typedef float f4v __attribute__((ext_vector_type(4)));
__device__ __forceinline__ float4 ntload4(const float4* p) {
    f4v v = __builtin_nontemporal_load((const f4v*)p);
    float4 r; r.x = v.x; r.y = v.y; r.z = v.z; r.w = v.w;
    return r;
}

// ---------------------------------------------------------------------------
// K1: gates1[r] = W_ih1[r,:].grad + W_hh1[r,:].hidden0 + b_ih1[r] + b_hh1[r]
// 512 persistent blocks x 256 threads; each block does 4 CONTIGUOUS rows
// sequentially -> 512 concurrent HBM read streams of 2 MB each (vs 2048
// of 512 KB in R5) for better DRAM page locality. W loads NT.
// ---------------------------------------------------------------------------
__global__ __launch_bounds__(256) void k_gemv1p(
    const float* __restrict__ U, const float* __restrict__ V,
    const float* __restrict__ Wih, const float* __restrict__ Whh,
    const float* __restrict__ bih, const float* __restrict__ bhh,
    const float* __restrict__ hidden, float* __restrict__ gates)
{
    __shared__ float s[4];
    const int t = threadIdx.x;
    const float4* __restrict__ U4 = (const float4*)U;
    const float4* __restrict__ V4 = (const float4*)V;
    const float4* __restrict__ h4 = (const float4*)hidden;  // hidden[0]
    #pragma unroll 1
    for (int i = 0; i < 4; ++i) {
        const int r = blockIdx.x * 4 + i;
        const float4* __restrict__ Wrow = (const float4*)(Wih + (size_t)r * D_IN);
        float acc = 0.0f;
        #pragma unroll 4
        for (int idx = t; idx < 16384; idx += 256) {
            acc += dot4(ntload4(&Wrow[idx]), U4[idx]);
        }
        #pragma unroll 4
        for (int idx = t; idx < 16384; idx += 256) {
            acc += dot4(ntload4(&Wrow[idx + 16384]), V4[idx]);
        }
        if (t < 128) {
            const float4* __restrict__ Wh4 = (const float4*)(Whh + (size_t)r * H);
            acc += dot4(ntload4(&Wh4[t]), h4[t]);
        }
        #pragma unroll
        for (int off = 32; off > 0; off >>= 1) acc += __shfl_down(acc, off);
        if ((t & 63) == 0) s[t >> 6] = acc;
        __syncthreads();
        if (t == 0) {
            gates[r] = s[0] + s[1] + s[2] + s[3] + bih[r] + bhh[r];
        }
        __syncthreads();   // s reused next row
    }
}

// ---------------------------------------------------------------------------
// K2: fused cell1 + gemv2. 128 blocks x 1024 threads (16 waves = 16 rows).
// ---------------------------------------------------------------------------
__global__ __launch_bounds__(1024) void k_l2fused(
    const float* __restrict__ gates1, const float* __restrict__ cell_in,
    const float* __restrict__ hidden,
    const float* __restrict__ Wih2, const float* __restrict__ Whh2,
    const float* __restrict__ bih2, const float* __restrict__ bhh2,
    const float* __restrict__ W3, const float* __restrict__ b3,
    float* __restrict__ gates2, float* __restrict__ out)
{
    __shared__ float h0s[H];
    __shared__ float red[16];
    const int tid = threadIdx.x;
    if (tid < H) {
        float ig = sigmoidf_(gates1[tid]);
        float fg = sigmoidf_(gates1[H + tid]);
        float gg = tanhf(gates1[2*H + tid]);
        float og = sigmoidf_(gates1[3*H + tid]);
        float c  = fg * cell_in[tid] + ig * gg;   // cell[0]
        float h  = og * tanhf(c);
        h0s[tid] = h;
        if (blockIdx.x == 0) {
            out[OFF_H0 + tid] = h;
            out[OFF_C0 + tid] = c;
        }
    }
    __syncthreads();
    const int wv = tid >> 6, lane = tid & 63;
    const int row = blockIdx.x * 16 + wv;
    const float4* __restrict__ Wr = (const float4*)(Wih2 + (size_t)row * H);
    const float4* __restrict__ Hr = (const float4*)(Whh2 + (size_t)row * H);
    const float4* h4 = (const float4*)h0s;
    const float4* __restrict__ y4 = (const float4*)(hidden + H);  // hidden[1]
    float acc = dot4(ntload4(&Wr[lane]),      h4[lane])
              + dot4(ntload4(&Hr[lane]),      y4[lane])
              + dot4(ntload4(&Wr[lane + 64]), h4[lane + 64])
              + dot4(ntload4(&Hr[lane + 64]), y4[lane + 64]);
    #pragma unroll
    for (int off = 32; off > 0; off >>= 1) acc += __shfl_down(acc, off);
    if (lane == 0) gates2[row] = acc + bih2[row] + bhh2[row];

    if (blockIdx.x == 0) {
        float p = (tid < H) ? h0s[tid] * W3[tid] : 0.0f;
        #pragma unroll
        for (int off = 32; off > 0; off >>= 1) p += __shfl_down(p, off);
        if (lane == 0) red[wv] = p;
        __syncthreads();
        if (tid == 0) {
            float v = b3[0];
            #pragma unroll
            for (int i = 0; i < 16; ++i) v += red[i];
            v = fminf(fmaxf(v, 0.0f), 1.0f);
            out[OFF_MC] = fminf(2.0f * v, 1.0f);
        }
    }
}

// ---------------------------------------------------------------------------
// K3: fused cell2 + out_g. 1024 blocks x 1024 threads (16 waves = 16 rows).
// Every block recomputes h1 from gates2 into LDS; block 0 writes h1/c1 and
// step_size. Saves one kernel launch vs separate cell2.
// ---------------------------------------------------------------------------
__global__ __launch_bounds__(1024) void k_l3fused(
    const float* __restrict__ gates2, const float* __restrict__ cell_in,
    const float* __restrict__ W1, const float* __restrict__ b1,
    const float* __restrict__ W2, const float* __restrict__ b2,
    float* __restrict__ out)
{
    __shared__ float h1s[H];
    __shared__ float red[16];
    const int tid = threadIdx.x;
    if (tid < H) {
        float ig = sigmoidf_(gates2[tid]);
        float fg = sigmoidf_(gates2[H + tid]);
        float gg = tanhf(gates2[2*H + tid]);
        float og = sigmoidf_(gates2[3*H + tid]);
        float c  = fg * cell_in[H + tid] + ig * gg;  // cell[1]
        float h  = og * tanhf(c);
        h1s[tid] = h;
        if (blockIdx.x == 0) {
            out[OFF_H1 + tid] = h;
            out[OFF_C1 + tid] = c;
        }
    }
    __syncthreads();
    const int wv = tid >> 6, lane = tid & 63;
    const int row = blockIdx.x * 16 + wv;
    const float4* __restrict__ Wr = (const float4*)(W1 + (size_t)row * H);
    const float4* h4 = (const float4*)h1s;
    float acc = dot4(ntload4(&Wr[lane]),      h4[lane])
              + dot4(ntload4(&Wr[lane + 64]), h4[lane + 64]);
    #pragma unroll
    for (int off = 32; off > 0; off >>= 1) acc += __shfl_down(acc, off);
    if (lane == 0) out[row] = acc + b1[row];

    if (blockIdx.x == 0) {
        float p = (tid < H) ? h1s[tid] * W2[tid] : 0.0f;
        #pragma unroll
        for (int off = 32; off > 0; off >>= 1) p += __shfl_down(p, off);
        if (lane == 0) red[wv] = p;
        __syncthreads();
        if (tid == 0) {
            float v = b2[0];
            #pragma unroll
            for (int i = 0; i < 16; ++i) v += red[i];
            out[OFF_STEP] = fminf(fmaxf(v, 1e-7f), 0.005f);
        }
    }
}

extern "C" void kernel_launch(void* const* d_in, const int* in_sizes, int n_in,
                              void* d_out, int out_size, void* d_ws, size_t ws_size,
                              hipStream_t stream) {
    const float* dL_dU  = (const float*)d_in[0];
    const float* dL_dV  = (const float*)d_in[1];
    const float* hidden = (const float*)d_in[2];
    const float* cell   = (const float*)d_in[3];
    const float* W_ih1  = (const float*)d_in[4];
    const float* W_hh1  = (const float*)d_in[5];
    const float* b_ih1  = (const float*)d_in[6];
    const float* b_hh1  = (const float*)d_in[7];
    const float* W_ih2  = (const float*)d_in[8];
    const float* W_hh2  = (const float*)d_in[9];
    const float* b_ih2  = (const float*)d_in[10];
    const float* b_hh2  = (const float*)d_in[11];
    const float* W1     = (const float*)d_in[12];
    const float* b1     = (const float*)d_in[13];
    const float* W2     = (const float*)d_in[14];
    const float* b2     = (const float*)d_in[15];
    const float* W3     = (const float*)d_in[16];
    const float* b3     = (const float*)d_in[17];

    float* out = (float*)d_out;
    float* ws  = (float*)d_ws;
    float* gates1 = ws;             // 2048
    float* gates2 = ws + 2048;      // 2048

    k_gemv1p<<<512, 256, 0, stream>>>(dL_dU, dL_dV, W_ih1, W_hh1,
                                      b_ih1, b_hh1, hidden, gates1);
    k_l2fused<<<G4 / 16, 1024, 0, stream>>>(gates1, cell, hidden,
                                            W_ih2, W_hh2, b_ih2, b_hh2,
                                            W3, b3, gates2, out);
    k_l3fused<<<OUTN / 16, 1024, 0, stream>>>(gates2, cell, W1, b1, W2, b2, out);
    (void)in_sizes; (void)n_in; (void)out_size; (void)ws_size;
}